// Round 18
// baseline (365.354 us; speedup 1.0000x reference)
//
#include <hip/hip_runtime.h>
#include <math.h>

#define NC 2000
#define NP 1500
#define NA 40
#define LP 512
#define BSZ 4096
#define NW 8000
#define KPC 2048
#define KPP 1536

typedef _Float16 half8_t __attribute__((ext_vector_type(8)));
typedef _Float16 half4_t __attribute__((ext_vector_type(4)));
typedef float f32x4 __attribute__((ext_vector_type(4)));

struct CnnS { half8_t bufA8[62 * 16]; half8_t bufB8[62 * 16]; };     // 31744 B
struct GnnS { _Float16 xs[48 * 72]; _Float16 hsT[64 * 72]; };        // 16128 B
struct MlpS { float cb[4][16][17]; };                                // 4352 B
struct EpiS { float Ys[64][68]; float Ws[64][64]; };                 // 33792 B

__device__ __forceinline__ int swz_off(int row, int half_col)
{
    int b = half_col >> 3;
    return row * 128 + (((b & 8) | ((b ^ row) & 7)) << 3) + (half_col & 7);
}

// =============== one-time prep (unchanged from round 16) ===============
__global__ void prep_all(
    const float* __restrict__ K_cnn, _Float16* __restrict__ wtab,
    const float* __restrict__ ew, _Float16* __restrict__ ehp,
    const float* __restrict__ df, const float* __restrict__ pf,
    const float* __restrict__ wd1, const float* __restrict__ wd2, const float* __restrict__ wd3,
    const float* __restrict__ wp1, const float* __restrict__ wp2, const float* __restrict__ wp3,
    const float* __restrict__ wo1, const float* __restrict__ wo2, const float* __restrict__ wo3,
    _Float16* __restrict__ dfh, _Float16* __restrict__ pfh,
    _Float16* __restrict__ wd1t, _Float16* __restrict__ wd2t, _Float16* __restrict__ wd3t,
    _Float16* __restrict__ wp1t, _Float16* __restrict__ wp2t, _Float16* __restrict__ wp3t,
    _Float16* __restrict__ wo1t, _Float16* __restrict__ wo2t, _Float16* __restrict__ wo3t,
    const float* __restrict__ wgnn, _Float16* __restrict__ wgt,
    const float* __restrict__ Ac, const float* __restrict__ Ap,
    const float* __restrict__ Xc, const float* __restrict__ Xp,
    _Float16* __restrict__ Ahc, _Float16* __restrict__ Ahp,
    _Float16* __restrict__ Xtc, _Float16* __restrict__ Xtp,
    _Float16* __restrict__ Xtca, _Float16* __restrict__ Xtpa)
{
    int j = blockIdx.x * 256 + threadIdx.x;
    if (j < 16896) {
        int L = j / 5632, rem = j % 5632;
        int dr = rem >> 9, r2 = rem & 511, ln = r2 >> 3, i = r2 & 7;
        int dc = 8 * (ln >> 4) + i - (ln & 15);
        float v = (dc >= 0 && dc < 11) ? K_cnn[L * 121 + dr * 11 + dc] : 0.f;
        wtab[j] = (_Float16)v;
        return;
    }
    j -= 16896;
    if (j < NW * 80) {
        int w = j / 80, h = j - w * 80;
        float v = (h >= 13 && h < 77) ? ew[w * 64 + (h - 13)] : 0.f;
        ehp[j] = (_Float16)v;
        return;
    }
    j -= NW * 80;
    if (j < 2048000) { dfh[j] = (_Float16)df[j]; return; }
    j -= 2048000;
    if (j < 1536000) { pfh[j] = (_Float16)pf[j]; return; }
    j -= 1536000;
    if (j < 131072) { int n = j >> 10, k = j & 1023; wd1t[j] = (_Float16)wd1[k * 128 + n]; return; }
    j -= 131072;
    if (j < 8192)  { int n = j >> 7, k = j & 127; wd2t[j] = (_Float16)wd2[k * 64 + n]; return; }
    j -= 8192;
    if (j < 4096)  { int n = j >> 6, k = j & 63; wd3t[j] = (_Float16)wd3[k * 64 + n]; return; }
    j -= 4096;
    if (j < 131072) { int n = j >> 10, k = j & 1023; wp1t[j] = (_Float16)wp1[k * 128 + n]; return; }
    j -= 131072;
    if (j < 8192)  { int n = j >> 7, k = j & 127; wp2t[j] = (_Float16)wp2[k * 64 + n]; return; }
    j -= 8192;
    if (j < 4096)  { int n = j >> 6, k = j & 63; wp3t[j] = (_Float16)wp3[k * 64 + n]; return; }
    j -= 4096;
    if (j < 98304) { int n = j / 384, k = j - n * 384; wo1t[j] = (_Float16)wo1[k * 256 + n]; return; }
    j -= 98304;
    if (j < 65536) { int n = j >> 8, k = j & 255; wo2t[j] = (_Float16)wo2[k * 256 + n]; return; }
    j -= 65536;
    if (j < 65536) { int n = j >> 8, k = j & 255; wo3t[j] = (_Float16)wo3[k * 256 + n]; return; }
    j -= 65536;
    if (j < 12288) { int l = j >> 12, rem = j & 4095, nn = rem >> 6, k = rem & 63;
                     wgt[j] = (_Float16)wgnn[l * 4096 + k * 64 + nn]; return; }
    j -= 12288;
    if (j < KPC * KPC) {
        int r = j >> 11, c = j & (KPC - 1);
        Ahc[j] = (_Float16)((r < NC && c < NC) ? Ac[(size_t)r * NC + c] : 0.f);
        return;
    }
    j -= KPC * KPC;
    if (j < KPP * KPP) {
        int r = j / KPP, c = j - r * KPP;
        Ahp[j] = (_Float16)((r < NP && c < NP) ? Ap[(size_t)r * NP + c] : 0.f);
        return;
    }
    j -= KPP * KPP;
    if (j < 64 * KPC) {
        int c = j >> 11, r = j & (KPC - 1);
        Xtc[j] = (_Float16)((r < NC) ? Xc[(size_t)r * 64 + c] : 0.f);
        return;
    }
    j -= 64 * KPC;
    if (j < 64 * KPP) {
        int c = j / KPP, r = j - c * KPP;
        Xtp[j] = (_Float16)((r < NP) ? Xp[(size_t)r * 64 + c] : 0.f);
        return;
    }
    j -= 64 * KPP;
    if (j < 64 * KPC) { Xtca[j] = (_Float16)0.f; return; }
    j -= 64 * KPC;
    if (j < 64 * KPP) { Xtpa[j] = (_Float16)0.f; }
}
#define PREP_TOTAL (16896 + NW * 80 + 2048000 + 1536000 + 131072 + 8192 + 4096 + 131072 + 8192 + 4096 + 98304 + 65536 + 65536 + 12288 + KPC * KPC + KPP * KPP + 64 * KPC + 64 * KPP + 64 * KPC + 64 * KPP)

// ====================== device bodies (validated round-16 math) ======================
__device__ __forceinline__ void gnn_body(GnnS& G, int n,
    const int* __restrict__ compounds, const float* __restrict__ adjacencies,
    const float* __restrict__ embed_fp, const _Float16* __restrict__ wgt,
    const float* __restrict__ b_gnn, _Float16* __restrict__ comp_h)
{
    const int tid = threadIdx.x, lane = tid & 63, wid = tid >> 6;
    const int m = lane & 15, g = lane >> 4;
    const int colL = wid * 16 + m;

    for (int j = tid; j < 48 * 64; j += 256) {
        int r = j >> 6, c = j & 63;
        _Float16 v = (_Float16)0.f;
        if (r < 40) v = (_Float16)embed_fp[(size_t)compounds[n * NA + r] * 64 + c];
        G.xs[r * 72 + c] = v;
    }
    for (int j = tid; j < 64 * 72 / 8; j += 256) ((half8_t*)G.hsT)[j] = (half8_t){};

    half8_t adjf[3][2];
    #pragma unroll
    for (int t = 0; t < 3; ++t)
        #pragma unroll
        for (int s = 0; s < 2; ++s) {
            half8_t v = {};
            int row = t * 16 + m, k0 = s * 32 + 8 * g;
            if (row < 40 && k0 < 40) {
                const float* src = &adjacencies[(size_t)n * 1600 + row * 40 + k0];
                #pragma unroll
                for (int i = 0; i < 8; ++i) v[i] = (_Float16)src[i];
            }
            adjf[t][s] = v;
        }
    __syncthreads();

    for (int l = 0; l < 3; ++l) {
        float bcol = b_gnn[l * 64 + colL];
        #pragma unroll
        for (int t = 0; t < 3; ++t) {
            f32x4 acc = {bcol, bcol, bcol, bcol};
            #pragma unroll
            for (int s = 0; s < 2; ++s) {
                half8_t a = *(const half8_t*)&G.xs[(t * 16 + m) * 72 + s * 32 + 8 * g];
                half8_t b = *(const half8_t*)&wgt[(size_t)(l * 64 + colL) * 64 + s * 32 + 8 * g];
                acc = __builtin_amdgcn_mfma_f32_16x16x32_f16(a, b, acc, 0, 0, 0);
            }
            half4_t h4;
            #pragma unroll
            for (int j = 0; j < 4; ++j) h4[j] = (_Float16)fmaxf(acc[j], 0.f);
            *(half4_t*)&G.hsT[colL * 72 + t * 16 + 4 * g] = h4;
        }
        __syncthreads();
        #pragma unroll
        for (int t = 0; t < 3; ++t) {
            f32x4 acc;
            #pragma unroll
            for (int j = 0; j < 4; ++j)
                acc[j] = (float)G.xs[(t * 16 + 4 * g + j) * 72 + colL];
            #pragma unroll
            for (int s = 0; s < 2; ++s) {
                half8_t b = *(const half8_t*)&G.hsT[colL * 72 + s * 32 + 8 * g];
                acc = __builtin_amdgcn_mfma_f32_16x16x32_f16(adjf[t][s], b, acc, 0, 0, 0);
            }
            #pragma unroll
            for (int j = 0; j < 4; ++j)
                G.xs[(t * 16 + 4 * g + j) * 72 + colL] = (_Float16)acc[j];
        }
        __syncthreads();
    }
    if (tid < 64) {
        float s = 0.f;
        for (int r = 0; r < 40; ++r) s += (float)G.xs[r * 72 + tid];
        comp_h[n * 64 + tid] = (_Float16)(s * (1.0f / 40.0f));
    }
}

__device__ __forceinline__ void cnn_body(CnnS& S, int cb_,
    const int* __restrict__ proteins, const _Float16* __restrict__ ehp,
    const half8_t* __restrict__ wtab, const float* __restrict__ b_cnn,
    float* __restrict__ prot_part)
{
    _Float16* bufA = (_Float16*)S.bufA8;
    _Float16* bufB = (_Float16*)S.bufB8;
    half8_t* bufA8 = S.bufA8;
    half8_t* bufB8 = S.bufB8;
    const int tid = threadIdx.x, lane = tid & 63, wid = tid >> 6;
    const int tile = cb_ & 15, p = cb_ >> 4;
    const int t0 = tile * 32;
    const int c0 = wid * 16;
    const int m = lane & 15, g = lane >> 4;

    half8_t z = {};
    for (int e = tid; e < 62 * 9; e += 256) {
        int i = e / 9, a = 1 + (e - 9 * i);
        int gr = t0 - 15 + i;
        half8_t v = z;
        if (gr >= 0 && gr < LP)
            v = *(const half8_t*)&ehp[(size_t)proteins[p * LP + gr] * 80 + 8 * a];
        *(half8_t*)&bufA[i * 128 + (((a & 8) | ((a ^ i) & 7)) << 3)] = v;
    }
    for (int e = tid; e < 62 * 4; e += 256) {
        int i = e >> 2, w = e & 3;
        if (w == 0)      bufA8[i * 16 + (8 | ((10 ^ i) & 7))] = z;
        else if (w == 1) bufB8[i * 16 + ((1 ^ i) & 7)] = z;
        else {
            int blk = 7 + w;
            bufB8[i * 16 + ((blk & 8) | ((blk ^ i) & 7))] = z;
        }
    }

    half8_t wf[11];
    auto load_wf = [&](int L) {
        #pragma unroll
        for (int dr = 0; dr < 11; ++dr) wf[dr] = wtab[L * 11 * 64 + dr * 64 + lane];
    };
    auto conv_tile = [&](const _Float16* src, int r0, float bias) -> f32x4 {
        f32x4 acc = {bias, bias, bias, bias};
        const int B0 = (c0 + 8) >> 3;
        #pragma unroll
        for (int dr = 0; dr < 11; ++dr) {
            int R = r0 - 5 + dr + m;
            int b = B0 + g;
            half8_t a = *(const half8_t*)&src[R * 128 + (((b & 8) | ((b ^ R) & 7)) << 3)];
            acc = __builtin_amdgcn_mfma_f32_16x16x32_f16(a, wf[dr], acc, 0, 0, 0);
        }
        return acc;
    };
    auto store_tile = [&](_Float16* dst, int r0, f32x4 acc) {
        int pc = c0 + 13 + m;
        #pragma unroll
        for (int j = 0; j < 4; ++j) {
            int row = r0 + 4 * g + j;
            int og = t0 - 15 + row;
            float v = fmaxf(acc[j], 0.f);
            dst[swz_off(row, pc)] = (_Float16)((og >= 0 && og < LP) ? v : 0.f);
        }
    };

    load_wf(0);
    __syncthreads();
    {
        float b0 = b_cnn[0];
        const int r0s[4] = {5, 21, 37, 41};
        #pragma unroll
        for (int k = 0; k < 4; ++k) store_tile(bufB, r0s[k], conv_tile(bufA, r0s[k], b0));
    }
    __syncthreads();
    load_wf(1);
    {
        float b1 = b_cnn[1];
        const int r0s[3] = {10, 26, 36};
        #pragma unroll
        for (int k = 0; k < 3; ++k) store_tile(bufA, r0s[k], conv_tile(bufB, r0s[k], b1));
    }
    __syncthreads();
    load_wf(2);
    {
        float b2 = b_cnn[2];
        float cs = 0.f;
        const int r0s[2] = {15, 31};
        #pragma unroll
        for (int k = 0; k < 2; ++k) {
            f32x4 acc = conv_tile(bufA, r0s[k], b2);
            #pragma unroll
            for (int j = 0; j < 4; ++j) cs += fmaxf(acc[j], 0.f);
        }
        cs += __shfl_xor(cs, 16, 64);
        cs += __shfl_xor(cs, 32, 64);
        if (lane < 16)
            prot_part[((size_t)p * 16 + tile) * 64 + c0 + lane] = cs;
    }
}

__device__ __forceinline__ void spk_body(int x, int y,
    const _Float16* __restrict__ Ah, const _Float16* __restrict__ Xt,
    float* __restrict__ part, int M, int Kp)
{
    const int tid = threadIdx.x, wid = tid >> 6, lane = tid & 63;
    const int m = lane & 15, g = lane >> 4;
    const int row0 = x * 64 + wid * 16;
    const int chunk = Kp >> 3, k0 = y * chunk;
    const _Float16* Apr = Ah + (size_t)(row0 + m) * Kp + 8 * g;
    f32x4 acc[4] = {};
    for (int kb = k0; kb < k0 + chunk; kb += 32) {
        half8_t af = *(const half8_t*)&Apr[kb];
        #pragma unroll
        for (int t = 0; t < 4; ++t) {
            half8_t bf = *(const half8_t*)&Xt[(size_t)(t * 16 + m) * Kp + kb + 8 * g];
            acc[t] = __builtin_amdgcn_mfma_f32_16x16x32_f16(af, bf, acc[t], 0, 0, 0);
        }
    }
    #pragma unroll
    for (int t = 0; t < 4; ++t)
        #pragma unroll
        for (int j = 0; j < 4; ++j) {
            int row = row0 + 4 * g + j;
            if (row < M) part[((size_t)y * M + row) * 64 + t * 16 + m] = acc[t][j];
        }
}

__device__ __forceinline__ void epi_body(EpiS& S, int x,
    const float* __restrict__ part, int M, const float* __restrict__ W,
    const float* __restrict__ bias, _Float16* __restrict__ H,
    _Float16* __restrict__ XtN, int Kp)
{
    const int rb = x * 64;
    const int tid = threadIdx.x;
    for (int j = tid; j < 4096; j += 256) S.Ws[j >> 6][j & 63] = W[j];
    for (int j = tid; j < 4096; j += 256) {
        int r = j >> 6, c = j & 63;
        float sum = 0.f;
        if (rb + r < M)
            for (int t = 0; t < 8; ++t) sum += part[((size_t)t * M + rb + r) * 64 + c];
        S.Ys[r][c] = sum;
    }
    __syncthreads();
    const int tx = tid & 15, ty = tid >> 4;
    float acc[4][4];
    #pragma unroll
    for (int i = 0; i < 4; ++i)
        #pragma unroll
        for (int j = 0; j < 4; ++j) acc[i][j] = bias[tx * 4 + j];
    for (int d = 0; d < 64; ++d) {
        float a0 = S.Ys[ty * 4 + 0][d], a1 = S.Ys[ty * 4 + 1][d];
        float a2 = S.Ys[ty * 4 + 2][d], a3 = S.Ys[ty * 4 + 3][d];
        float4 w4 = *(const float4*)&S.Ws[d][tx * 4];
        acc[0][0] += a0 * w4.x; acc[0][1] += a0 * w4.y; acc[0][2] += a0 * w4.z; acc[0][3] += a0 * w4.w;
        acc[1][0] += a1 * w4.x; acc[1][1] += a1 * w4.y; acc[1][2] += a1 * w4.z; acc[1][3] += a1 * w4.w;
        acc[2][0] += a2 * w4.x; acc[2][1] += a2 * w4.y; acc[2][2] += a2 * w4.z; acc[2][3] += a2 * w4.w;
        acc[3][0] += a3 * w4.x; acc[3][1] += a3 * w4.y; acc[3][2] += a3 * w4.z; acc[3][3] += a3 * w4.w;
    }
    #pragma unroll
    for (int i = 0; i < 4; ++i) {
        int row = rb + ty * 4 + i;
        if (row < M) {
            #pragma unroll
            for (int j = 0; j < 4; ++j) {
                int col = tx * 4 + j;
                float v = fmaxf(acc[i][j], 0.f);
                if (H)   H[(size_t)row * 64 + col] = (_Float16)v;
                if (XtN) XtN[(size_t)col * Kp + row] = (_Float16)v;
            }
        }
    }
}

template<int NT, bool GATHER>
__device__ __forceinline__ void mlp_body(MlpS& S, int x, int y,
    const _Float16* __restrict__ A, const int* __restrict__ idx,
    const _Float16* __restrict__ Bt, const float* __restrict__ bias,
    _Float16* __restrict__ C, int K, int N)
{
    const int tid = threadIdx.x, wid = tid >> 6, lane = tid & 63;
    const int m = lane & 15, g = lane >> 4;
    const int row0 = x * 64 + wid * 16;
    const int col0 = y * (NT * 16);
    size_t arow = GATHER ? (size_t)idx[row0 + m] : (size_t)(row0 + m);
    const _Float16* Ap = A + arow * (size_t)K + 8 * g;
    f32x4 acc[NT] = {};
    for (int kb = 0; kb < K; kb += 32) {
        half8_t af = *(const half8_t*)&Ap[kb];
        #pragma unroll
        for (int t = 0; t < NT; ++t) {
            half8_t bf = *(const half8_t*)&Bt[(size_t)(col0 + t * 16 + m) * K + kb + 8 * g];
            acc[t] = __builtin_amdgcn_mfma_f32_16x16x32_f16(af, bf, acc[t], 0, 0, 0);
        }
    }
    const int rr = lane >> 2, c4 = (lane & 3) * 4;
    #pragma unroll
    for (int t = 0; t < NT; ++t) {
        #pragma unroll
        for (int j = 0; j < 4; ++j) S.cb[wid][4 * g + j][m] = acc[t][j];
        half4_t h;
        #pragma unroll
        for (int j = 0; j < 4; ++j)
            h[j] = (_Float16)fmaxf(S.cb[wid][rr][c4 + j] + bias[col0 + t * 16 + c4 + j], 0.f);
        *(half4_t*)&C[(size_t)(row0 + rr) * N + col0 + t * 16 + c4] = h;
    }
}

// =============== MEGA: GNN + CNN + spk1 + mlp1 in one dispatch ===============
#define MEGA_CNN0 NC
#define MEGA_SPK0 (NC + 16 * NP)
#define MEGA_MLP0 (MEGA_SPK0 + 512)
#define MEGA_TOTAL (MEGA_MLP0 + 512)

__global__ __launch_bounds__(256) void mega_kernel(
    const int* __restrict__ proteins, const _Float16* __restrict__ ehp,
    const half8_t* __restrict__ wtab, const float* __restrict__ b_cnn,
    float* __restrict__ prot_part,
    const int* __restrict__ compounds, const float* __restrict__ adjacencies,
    const float* __restrict__ embed_fp, const _Float16* __restrict__ wgt,
    const float* __restrict__ b_gnn, _Float16* __restrict__ comp_h,
    const _Float16* __restrict__ Ah_c, const _Float16* __restrict__ Xt_c, float* __restrict__ part_c,
    const _Float16* __restrict__ Ah_p, const _Float16* __restrict__ Xt_p, float* __restrict__ part_p,
    const _Float16* __restrict__ drug_h, const int* __restrict__ idx_c,
    const _Float16* __restrict__ wd1t, const float* __restrict__ bd1, _Float16* __restrict__ fd1h,
    const _Float16* __restrict__ protf_h, const int* __restrict__ idx_p,
    const _Float16* __restrict__ wp1t, const float* __restrict__ bp1, _Float16* __restrict__ fp1h)
{
    __shared__ union { CnnS c; GnnS g; MlpS m; } sm;
    const int bx = blockIdx.x;

    if (bx >= MEGA_MLP0) {
        int idx = bx - MEGA_MLP0;
        int z = idx >> 8, rem = idx & 255, y = rem >> 6, x = rem & 63;
        if (z == 0) mlp_body<2, true>(sm.m, x, y, drug_h, idx_c, wd1t, bd1, fd1h, 1024, 128);
        else        mlp_body<2, true>(sm.m, x, y, protf_h, idx_p, wp1t, bp1, fp1h, 1024, 128);
        return;
    }
    if (bx >= MEGA_SPK0) {
        int idx = bx - MEGA_SPK0;
        int z = idx >> 8, rem = idx & 255, y = rem >> 5, x = rem & 31;
        if (z == 0)      spk_body(x, y, Ah_c, Xt_c, part_c, NC, KPC);
        else if (x < 24) spk_body(x, y, Ah_p, Xt_p, part_p, NP, KPP);
        return;
    }
    if (bx < MEGA_CNN0) {
        gnn_body(sm.g, bx, compounds, adjacencies, embed_fp, wgt, b_gnn, comp_h);
        return;
    }
    cnn_body(sm.c, bx - MEGA_CNN0, proteins, ehp, wtab, b_cnn, prot_part);
}

// =============== tail1: cnn_reduce + epi1 + mlp2 ===============
__global__ __launch_bounds__(256) void tail1(
    const float* __restrict__ prot_part, _Float16* __restrict__ prot_h,
    const float* __restrict__ part_c, const float* __restrict__ W_gcn_d, const float* __restrict__ b_gcn_d,
    _Float16* __restrict__ Xt_ca,
    const float* __restrict__ part_p, const float* __restrict__ W_gcn_p, const float* __restrict__ b_gcn_p,
    _Float16* __restrict__ Xt_pa,
    const _Float16* __restrict__ fd1h, const _Float16* __restrict__ wd2t, const float* __restrict__ bd2,
    _Float16* __restrict__ fd2h,
    const _Float16* __restrict__ fp1h, const _Float16* __restrict__ wp2t, const float* __restrict__ bp2,
    _Float16* __restrict__ fp2h)
{
    __shared__ union { EpiS e; MlpS m; } sm;
    int bx = blockIdx.x;
    const int tid = threadIdx.x;
    if (bx < 375) {
        int p = bx * 4 + (tid >> 6), c = tid & 63;
        float s = 0.f;
        for (int t = 0; t < 16; ++t) s += prot_part[((size_t)p * 16 + t) * 64 + c];
        prot_h[p * 64 + c] = (_Float16)(s * (1.0f / 512.0f));
        return;
    }
    bx -= 375;
    if (bx < 64) {
        int z = bx >> 5, x = bx & 31;
        if (z == 0)      epi_body(sm.e, x, part_c, NC, W_gcn_d, b_gcn_d, nullptr, Xt_ca, KPC);
        else if (x < 24) epi_body(sm.e, x, part_p, NP, W_gcn_p, b_gcn_p, nullptr, Xt_pa, KPP);
        return;
    }
    bx -= 64;
    {
        int z = bx >> 8, rem = bx & 255, y = rem >> 6, x = rem & 63;
        if (z == 0) mlp_body<1, false>(sm.m, x, y, fd1h, nullptr, wd2t, bd2, fd2h, 128, 64);
        else        mlp_body<1, false>(sm.m, x, y, fp1h, nullptr, wp2t, bp2, fp2h, 128, 64);
    }
}

// =============== tail2: spk2 + mlp3 ===============
__global__ __launch_bounds__(256) void tail2(
    const _Float16* __restrict__ Ah_c, const _Float16* __restrict__ Xt_ca, float* __restrict__ part_c,
    const _Float16* __restrict__ Ah_p, const _Float16* __restrict__ Xt_pa, float* __restrict__ part_p,
    const _Float16* __restrict__ fd2h, const _Float16* __restrict__ wd3t, const float* __restrict__ bd3,
    _Float16* __restrict__ fd3h,
    const _Float16* __restrict__ fp2h, const _Float16* __restrict__ wp3t, const float* __restrict__ bp3,
    _Float16* __restrict__ fp3h)
{
    __shared__ MlpS sm;
    int bx = blockIdx.x;
    if (bx < 512) {
        int z = bx >> 8, rem = bx & 255, y = rem >> 5, x = rem & 31;
        if (z == 0)      spk_body(x, y, Ah_c, Xt_ca, part_c, NC, KPC);
        else if (x < 24) spk_body(x, y, Ah_p, Xt_pa, part_p, NP, KPP);
        return;
    }
    bx -= 512;
    {
        int z = bx >> 8, rem = bx & 255, y = rem >> 6, x = rem & 63;
        if (z == 0) mlp_body<1, false>(sm, x, y, fd2h, nullptr, wd3t, bd3, fd3h, 64, 64);
        else        mlp_body<1, false>(sm, x, y, fp2h, nullptr, wp3t, bp3, fp3h, 64, 64);
    }
}

// =============== epi2 (dual) ===============
__global__ __launch_bounds__(256) void epi2_kernel(
    const float* __restrict__ part_c, const float* __restrict__ W0, const float* __restrict__ b0,
    _Float16* __restrict__ Xcb_h,
    const float* __restrict__ part_p, const float* __restrict__ W1, const float* __restrict__ b1,
    _Float16* __restrict__ Xpb_h)
{
    __shared__ EpiS sm;
    int bx = blockIdx.x;
    int z = bx >> 5, x = bx & 31;
    if (z == 0)      epi_body(sm, x, part_c, NC, W0, b0, Xcb_h, nullptr, KPC);
    else if (x < 24) epi_body(sm, x, part_p, NP, W1, b1, Xpb_h, nullptr, KPP);
}

// =============== head kernels ===============
__global__ __launch_bounds__(256) void mfma_head1(
    const int* __restrict__ idx_c, const int* __restrict__ idx_p,
    const _Float16* __restrict__ ci, const _Float16* __restrict__ xc, const _Float16* __restrict__ fd,
    const _Float16* __restrict__ pi, const _Float16* __restrict__ xp, const _Float16* __restrict__ fp,
    const _Float16* __restrict__ Bt, const float* __restrict__ bias, _Float16* __restrict__ C)
{
    const int tid = threadIdx.x, wid = tid >> 6, lane = tid & 63;
    const int m = lane & 15, g = lane >> 4;
    const int row0 = blockIdx.x * 64 + wid * 16;
    const int col0 = blockIdx.y * 32;
    int ic = idx_c[row0 + m], ip = idx_p[row0 + m];
    const _Float16* segs[6] = {
        ci + (size_t)ic * 64 + 8 * g,  xc + (size_t)ic * 64 + 8 * g,
        fd + (size_t)(row0 + m) * 64 + 8 * g,
        pi + (size_t)ip * 64 + 8 * g,  xp + (size_t)ip * 64 + 8 * g,
        fp + (size_t)(row0 + m) * 64 + 8 * g };
    f32x4 acc[2] = {};
    #pragma unroll
    for (int kb = 0; kb < 384; kb += 32) {
        half8_t af = *(const half8_t*)&segs[kb / 64][kb & 63];
        #pragma unroll
        for (int t = 0; t < 2; ++t) {
            half8_t bf = *(const half8_t*)&Bt[(size_t)(col0 + t * 16 + m) * 384 + kb + 8 * g];
            acc[t] = __builtin_amdgcn_mfma_f32_16x16x32_f16(af, bf, acc[t], 0, 0, 0);
        }
    }
    __shared__ MlpS sm;
    const int rr = lane >> 2, c4 = (lane & 3) * 4;
    #pragma unroll
    for (int t = 0; t < 2; ++t) {
        #pragma unroll
        for (int j = 0; j < 4; ++j) sm.cb[wid][4 * g + j][m] = acc[t][j];
        half4_t h;
        #pragma unroll
        for (int j = 0; j < 4; ++j)
            h[j] = (_Float16)fmaxf(sm.cb[wid][rr][c4 + j] + bias[col0 + t * 16 + c4 + j], 0.f);
        *(half4_t*)&C[(size_t)(row0 + rr) * 256 + col0 + t * 16 + c4] = h;
    }
}

__global__ __launch_bounds__(256) void mfma_head2(
    const _Float16* __restrict__ A, const _Float16* __restrict__ Bt,
    const float* __restrict__ bias, _Float16* __restrict__ C)
{
    __shared__ MlpS sm;
    mlp_body<2, false>(sm, blockIdx.x, blockIdx.y, A, nullptr, Bt, bias, C, 256, 256);
}

__global__ __launch_bounds__(256) void mfma_head3(
    const _Float16* __restrict__ A, const _Float16* __restrict__ Bt,
    const float* __restrict__ bias, const float* __restrict__ Wi, const float* __restrict__ bi,
    float* __restrict__ out)
{
    const int tid = threadIdx.x, wid = tid >> 6, lane = tid & 63;
    const int m = lane & 15, g = lane >> 4;
    const int row0 = blockIdx.x * 64 + wid * 16;
    const _Float16* Ap = A + (size_t)(row0 + m) * 256 + 8 * g;
    f32x4 acc[16] = {};
    for (int kb = 0; kb < 256; kb += 32) {
        half8_t af = *(const half8_t*)&Ap[kb];
        #pragma unroll
        for (int t = 0; t < 16; ++t) {
            half8_t bf = *(const half8_t*)&Bt[(size_t)(t * 16 + m) * 256 + kb + 8 * g];
            acc[t] = __builtin_amdgcn_mfma_f32_16x16x32_f16(af, bf, acc[t], 0, 0, 0);
        }
    }
    float p0[4] = {}, p1[4] = {};
    #pragma unroll
    for (int t = 0; t < 16; ++t) {
        float w0 = Wi[(t * 16 + m) * 2], w1 = Wi[(t * 16 + m) * 2 + 1];
        float bc = bias[t * 16 + m];
        #pragma unroll
        for (int j = 0; j < 4; ++j) {
            float v = fmaxf(acc[t][j] + bc, 0.f);
            p0[j] += v * w0; p1[j] += v * w1;
        }
    }
    #pragma unroll
    for (int d = 1; d < 16; d <<= 1) {
        #pragma unroll
        for (int j = 0; j < 4; ++j) {
            p0[j] += __shfl_xor(p0[j], d, 64);
            p1[j] += __shfl_xor(p1[j], d, 64);
        }
    }
    if (m == 0) {
        float B0 = bi[0], B1 = bi[1];
        #pragma unroll
        for (int j = 0; j < 4; ++j) {
            int r = row0 + 4 * g + j;
            out[r * 2 + 0] = 1.f / (1.f + expf(-(p0[j] + B0)));
            out[r * 2 + 1] = 1.f / (1.f + expf(-(p1[j] + B1)));
        }
    }
}

// ======================= launch =======================
extern "C" void kernel_launch(void* const* d_in, const int* in_sizes, int n_in,
                              void* d_out, int out_size, void* d_ws, size_t ws_size,
                              hipStream_t stream)
{
    const int*   idx_c        = (const int*)  d_in[0];
    const int*   idx_p        = (const int*)  d_in[1];
    const int*   compounds    = (const int*)  d_in[2];
    const int*   proteins     = (const int*)  d_in[3];
    const float* adjacencies  = (const float*)d_in[4];
    const float* A_c          = (const float*)d_in[5];
    const float* A_p          = (const float*)d_in[6];
    const float* embed_fp     = (const float*)d_in[7];
    const float* embed_word   = (const float*)d_in[8];
    const float* Xs_c         = (const float*)d_in[9];
    const float* Xs_p         = (const float*)d_in[10];
    const float* drug_feat    = (const float*)d_in[11];
    const float* protein_feat = (const float*)d_in[12];
    const float* W_gnn        = (const float*)d_in[13];
    const float* b_gnn        = (const float*)d_in[14];
    const float* K_cnn        = (const float*)d_in[15];
    const float* b_cnn        = (const float*)d_in[16];
    const float* W_gcn_d      = (const float*)d_in[17];
    const float* b_gcn_d      = (const float*)d_in[18];
    const float* W_gcn_p      = (const float*)d_in[19];
    const float* b_gcn_p      = (const float*)d_in[20];
    const float* Wd1 = (const float*)d_in[21]; const float* bd1 = (const float*)d_in[22];
    const float* Wd2 = (const float*)d_in[23]; const float* bd2 = (const float*)d_in[24];
    const float* Wd3 = (const float*)d_in[25]; const float* bd3 = (const float*)d_in[26];
    const float* Wp1 = (const float*)d_in[27]; const float* bp1 = (const float*)d_in[28];
    const float* Wp2 = (const float*)d_in[29]; const float* bp2 = (const float*)d_in[30];
    const float* Wp3 = (const float*)d_in[31]; const float* bp3 = (const float*)d_in[32];
    const float* Wo1 = (const float*)d_in[33]; const float* bo1 = (const float*)d_in[34];
    const float* Wo2 = (const float*)d_in[35]; const float* bo2 = (const float*)d_in[36];
    const float* Wo3 = (const float*)d_in[37]; const float* bo3 = (const float*)d_in[38];
    const float* W_int = (const float*)d_in[39]; const float* b_int = (const float*)d_in[40];

    float* ws = (float*)d_ws;
    float* prot_part = ws; ws += NP * 16 * 64;
    float* wtab_g    = ws; ws += 8448;
    float* ehp_g     = ws; ws += NW * 40;
    float* part_c    = ws; ws += 8 * NC * 64;
    float* part_p    = ws; ws += 8 * NP * 64;
    _Float16* Ah_c  = (_Float16*)ws; ws += KPC * KPC / 2;
    _Float16* Ah_p  = (_Float16*)ws; ws += KPP * KPP / 2;
    _Float16* Xt_c  = (_Float16*)ws; ws += 32 * KPC;
    _Float16* Xt_p  = (_Float16*)ws; ws += 32 * KPP;
    _Float16* Xt_ca = (_Float16*)ws; ws += 32 * KPC;
    _Float16* Xt_pa = (_Float16*)ws; ws += 32 * KPP;
    _Float16* wgt_g = (_Float16*)ws; ws += 6144;
    _Float16* comp_h  = (_Float16*)ws; ws += NC * 32;
    _Float16* prot_h  = (_Float16*)ws; ws += NP * 32;
    _Float16* Xcb_h   = (_Float16*)ws; ws += NC * 32;
    _Float16* Xpb_h   = (_Float16*)ws; ws += NP * 32;
    _Float16* drug_h  = (_Float16*)ws; ws += NC * 512;
    _Float16* protf_h = (_Float16*)ws; ws += NP * 512;
    _Float16* wd1t = (_Float16*)ws; ws += 65536;
    _Float16* wd2t = (_Float16*)ws; ws += 4096;
    _Float16* wd3t = (_Float16*)ws; ws += 2048;
    _Float16* wp1t = (_Float16*)ws; ws += 65536;
    _Float16* wp2t = (_Float16*)ws; ws += 4096;
    _Float16* wp3t = (_Float16*)ws; ws += 2048;
    _Float16* wo1t = (_Float16*)ws; ws += 49152;
    _Float16* wo2t = (_Float16*)ws; ws += 32768;
    _Float16* wo3t = (_Float16*)ws; ws += 32768;
    _Float16* fd1h = (_Float16*)ws; ws += BSZ * 64;
    _Float16* fd2h = (_Float16*)ws; ws += BSZ * 32;
    _Float16* fd3h = (_Float16*)ws; ws += BSZ * 32;
    _Float16* fp1h = (_Float16*)ws; ws += BSZ * 64;
    _Float16* fp2h = (_Float16*)ws; ws += BSZ * 32;
    _Float16* fp3h = (_Float16*)ws; ws += BSZ * 32;
    _Float16* h1h  = (_Float16*)ws; ws += BSZ * 128;
    _Float16* h2h  = (_Float16*)ws; ws += BSZ * 128;
    (void)ws_size; (void)in_sizes; (void)n_in; (void)out_size;

    prep_all<<<(PREP_TOTAL + 255) / 256, 256, 0, stream>>>(
        K_cnn, (_Float16*)wtab_g, embed_word, (_Float16*)ehp_g,
        drug_feat, protein_feat, Wd1, Wd2, Wd3, Wp1, Wp2, Wp3, Wo1, Wo2, Wo3,
        drug_h, protf_h, wd1t, wd2t, wd3t, wp1t, wp2t, wp3t, wo1t, wo2t, wo3t,
        W_gnn, wgt_g,
        A_c, A_p, Xs_c, Xs_p, Ah_c, Ah_p, Xt_c, Xt_p, Xt_ca, Xt_pa);
    mega_kernel<<<MEGA_TOTAL, 256, 0, stream>>>(
        proteins, (const _Float16*)ehp_g, (const half8_t*)wtab_g, b_cnn, prot_part,
        compounds, adjacencies, embed_fp, wgt_g, b_gnn, comp_h,
        Ah_c, Xt_c, part_c, Ah_p, Xt_p, part_p,
        drug_h, idx_c, wd1t, bd1, fd1h, protf_h, idx_p, wp1t, bp1, fp1h);
    tail1<<<375 + 64 + 512, 256, 0, stream>>>(
        prot_part, prot_h,
        part_c, W_gcn_d, b_gcn_d, Xt_ca, part_p, W_gcn_p, b_gcn_p, Xt_pa,
        fd1h, wd2t, bd2, fd2h, fp1h, wp2t, bp2, fp2h);
    tail2<<<512 + 512, 256, 0, stream>>>(
        Ah_c, Xt_ca, part_c, Ah_p, Xt_pa, part_p,
        fd2h, wd3t, bd3, fd3h, fp2h, wp3t, bp3, fp3h);
    epi2_kernel<<<64, 256, 0, stream>>>(
        part_c, W_gcn_d + 4096, b_gcn_d + 64, Xcb_h,
        part_p, W_gcn_p + 4096, b_gcn_p + 64, Xpb_h);
    mfma_head1<<<dim3(64, 8), 256, 0, stream>>>(idx_c, idx_p, comp_h, Xcb_h, fd3h,
                                                prot_h, Xpb_h, fp3h, wo1t, bo1, h1h);
    mfma_head2<<<dim3(64, 8), 256, 0, stream>>>(h1h, wo2t, bo2, h2h);
    mfma_head3<<<64, 256, 0, stream>>>(h2h, wo3t, bo3, W_int, b_int, (float*)d_out);
}

// Round 19
// 341.494 us; speedup vs baseline: 1.0699x; 1.0699x over previous
//
#include <hip/hip_runtime.h>
#include <math.h>

#define NC 2000
#define NP 1500
#define NA 40
#define LP 512
#define BSZ 4096
#define NW 8000
#define KPC 2048
#define KPP 1536

typedef _Float16 half8_t __attribute__((ext_vector_type(8)));
typedef _Float16 half4_t __attribute__((ext_vector_type(4)));
typedef float f32x4 __attribute__((ext_vector_type(4)));

struct CnnS { half8_t bufA8[62 * 16]; half8_t bufB8[62 * 16]; };     // 31744 B
struct GnnS { _Float16 xs[48 * 72]; _Float16 hsT[64 * 72]; };        // 16128 B
struct MlpS { float cb[4][16][17]; };                                // 4352 B
struct EpiS { float Ys[64][68]; float Ws[64][64]; };                 // 33792 B

__device__ __forceinline__ int swz_off(int row, int half_col)
{
    int b = half_col >> 3;
    return row * 128 + (((b & 8) | ((b ^ row) & 7)) << 3) + (half_col & 7);
}

// =============== one-time prep (validated) ===============
__global__ void prep_all(
    const float* __restrict__ K_cnn, _Float16* __restrict__ wtab,
    const float* __restrict__ ew, _Float16* __restrict__ ehp,
    const float* __restrict__ df, const float* __restrict__ pf,
    const float* __restrict__ wd1, const float* __restrict__ wd2, const float* __restrict__ wd3,
    const float* __restrict__ wp1, const float* __restrict__ wp2, const float* __restrict__ wp3,
    const float* __restrict__ wo1, const float* __restrict__ wo2, const float* __restrict__ wo3,
    _Float16* __restrict__ dfh, _Float16* __restrict__ pfh,
    _Float16* __restrict__ wd1t, _Float16* __restrict__ wd2t, _Float16* __restrict__ wd3t,
    _Float16* __restrict__ wp1t, _Float16* __restrict__ wp2t, _Float16* __restrict__ wp3t,
    _Float16* __restrict__ wo1t, _Float16* __restrict__ wo2t, _Float16* __restrict__ wo3t,
    const float* __restrict__ wgnn, _Float16* __restrict__ wgt,
    const float* __restrict__ Ac, const float* __restrict__ Ap,
    const float* __restrict__ Xc, const float* __restrict__ Xp,
    _Float16* __restrict__ Ahc, _Float16* __restrict__ Ahp,
    _Float16* __restrict__ Xtc, _Float16* __restrict__ Xtp,
    _Float16* __restrict__ Xtca, _Float16* __restrict__ Xtpa)
{
    int j = blockIdx.x * 256 + threadIdx.x;
    if (j < 16896) {
        int L = j / 5632, rem = j % 5632;
        int dr = rem >> 9, r2 = rem & 511, ln = r2 >> 3, i = r2 & 7;
        int dc = 8 * (ln >> 4) + i - (ln & 15);
        float v = (dc >= 0 && dc < 11) ? K_cnn[L * 121 + dr * 11 + dc] : 0.f;
        wtab[j] = (_Float16)v;
        return;
    }
    j -= 16896;
    if (j < NW * 80) {
        int w = j / 80, h = j - w * 80;
        float v = (h >= 13 && h < 77) ? ew[w * 64 + (h - 13)] : 0.f;
        ehp[j] = (_Float16)v;
        return;
    }
    j -= NW * 80;
    if (j < 2048000) { dfh[j] = (_Float16)df[j]; return; }
    j -= 2048000;
    if (j < 1536000) { pfh[j] = (_Float16)pf[j]; return; }
    j -= 1536000;
    if (j < 131072) { int n = j >> 10, k = j & 1023; wd1t[j] = (_Float16)wd1[k * 128 + n]; return; }
    j -= 131072;
    if (j < 8192)  { int n = j >> 7, k = j & 127; wd2t[j] = (_Float16)wd2[k * 64 + n]; return; }
    j -= 8192;
    if (j < 4096)  { int n = j >> 6, k = j & 63; wd3t[j] = (_Float16)wd3[k * 64 + n]; return; }
    j -= 4096;
    if (j < 131072) { int n = j >> 10, k = j & 1023; wp1t[j] = (_Float16)wp1[k * 128 + n]; return; }
    j -= 131072;
    if (j < 8192)  { int n = j >> 7, k = j & 127; wp2t[j] = (_Float16)wp2[k * 64 + n]; return; }
    j -= 8192;
    if (j < 4096)  { int n = j >> 6, k = j & 63; wp3t[j] = (_Float16)wp3[k * 64 + n]; return; }
    j -= 4096;
    if (j < 98304) { int n = j / 384, k = j - n * 384; wo1t[j] = (_Float16)wo1[k * 256 + n]; return; }
    j -= 98304;
    if (j < 65536) { int n = j >> 8, k = j & 255; wo2t[j] = (_Float16)wo2[k * 256 + n]; return; }
    j -= 65536;
    if (j < 65536) { int n = j >> 8, k = j & 255; wo3t[j] = (_Float16)wo3[k * 256 + n]; return; }
    j -= 65536;
    if (j < 12288) { int l = j >> 12, rem = j & 4095, nn = rem >> 6, k = rem & 63;
                     wgt[j] = (_Float16)wgnn[l * 4096 + k * 64 + nn]; return; }
    j -= 12288;
    if (j < KPC * KPC) {
        int r = j >> 11, c = j & (KPC - 1);
        Ahc[j] = (_Float16)((r < NC && c < NC) ? Ac[(size_t)r * NC + c] : 0.f);
        return;
    }
    j -= KPC * KPC;
    if (j < KPP * KPP) {
        int r = j / KPP, c = j - r * KPP;
        Ahp[j] = (_Float16)((r < NP && c < NP) ? Ap[(size_t)r * NP + c] : 0.f);
        return;
    }
    j -= KPP * KPP;
    if (j < 64 * KPC) {
        int c = j >> 11, r = j & (KPC - 1);
        Xtc[j] = (_Float16)((r < NC) ? Xc[(size_t)r * 64 + c] : 0.f);
        return;
    }
    j -= 64 * KPC;
    if (j < 64 * KPP) {
        int c = j / KPP, r = j - c * KPP;
        Xtp[j] = (_Float16)((r < NP) ? Xp[(size_t)r * 64 + c] : 0.f);
        return;
    }
    j -= 64 * KPP;
    if (j < 64 * KPC) { Xtca[j] = (_Float16)0.f; return; }
    j -= 64 * KPC;
    if (j < 64 * KPP) { Xtpa[j] = (_Float16)0.f; }
}
#define PREP_TOTAL (16896 + NW * 80 + 2048000 + 1536000 + 131072 + 8192 + 4096 + 131072 + 8192 + 4096 + 98304 + 65536 + 65536 + 12288 + KPC * KPC + KPP * KPP + 64 * KPC + 64 * KPP + 64 * KPC + 64 * KPP)

// ====================== device bodies (validated) ======================
__device__ __forceinline__ void gnn_body(GnnS& G, int n,
    const int* __restrict__ compounds, const float* __restrict__ adjacencies,
    const float* __restrict__ embed_fp, const _Float16* __restrict__ wgt,
    const float* __restrict__ b_gnn, _Float16* __restrict__ comp_h)
{
    const int tid = threadIdx.x, lane = tid & 63, wid = tid >> 6;
    const int m = lane & 15, g = lane >> 4;
    const int colL = wid * 16 + m;

    for (int j = tid; j < 48 * 64; j += 256) {
        int r = j >> 6, c = j & 63;
        _Float16 v = (_Float16)0.f;
        if (r < 40) v = (_Float16)embed_fp[(size_t)compounds[n * NA + r] * 64 + c];
        G.xs[r * 72 + c] = v;
    }
    for (int j = tid; j < 64 * 72 / 8; j += 256) ((half8_t*)G.hsT)[j] = (half8_t){};

    half8_t adjf[3][2];
    #pragma unroll
    for (int t = 0; t < 3; ++t)
        #pragma unroll
        for (int s = 0; s < 2; ++s) {
            half8_t v = {};
            int row = t * 16 + m, k0 = s * 32 + 8 * g;
            if (row < 40 && k0 < 40) {
                const float* src = &adjacencies[(size_t)n * 1600 + row * 40 + k0];
                #pragma unroll
                for (int i = 0; i < 8; ++i) v[i] = (_Float16)src[i];
            }
            adjf[t][s] = v;
        }
    __syncthreads();

    for (int l = 0; l < 3; ++l) {
        float bcol = b_gnn[l * 64 + colL];
        #pragma unroll
        for (int t = 0; t < 3; ++t) {
            f32x4 acc = {bcol, bcol, bcol, bcol};
            #pragma unroll
            for (int s = 0; s < 2; ++s) {
                half8_t a = *(const half8_t*)&G.xs[(t * 16 + m) * 72 + s * 32 + 8 * g];
                half8_t b = *(const half8_t*)&wgt[(size_t)(l * 64 + colL) * 64 + s * 32 + 8 * g];
                acc = __builtin_amdgcn_mfma_f32_16x16x32_f16(a, b, acc, 0, 0, 0);
            }
            half4_t h4;
            #pragma unroll
            for (int j = 0; j < 4; ++j) h4[j] = (_Float16)fmaxf(acc[j], 0.f);
            *(half4_t*)&G.hsT[colL * 72 + t * 16 + 4 * g] = h4;
        }
        __syncthreads();
        #pragma unroll
        for (int t = 0; t < 3; ++t) {
            f32x4 acc;
            #pragma unroll
            for (int j = 0; j < 4; ++j)
                acc[j] = (float)G.xs[(t * 16 + 4 * g + j) * 72 + colL];
            #pragma unroll
            for (int s = 0; s < 2; ++s) {
                half8_t b = *(const half8_t*)&G.hsT[colL * 72 + s * 32 + 8 * g];
                acc = __builtin_amdgcn_mfma_f32_16x16x32_f16(adjf[t][s], b, acc, 0, 0, 0);
            }
            #pragma unroll
            for (int j = 0; j < 4; ++j)
                G.xs[(t * 16 + 4 * g + j) * 72 + colL] = (_Float16)acc[j];
        }
        __syncthreads();
    }
    if (tid < 64) {
        float s = 0.f;
        for (int r = 0; r < 40; ++r) s += (float)G.xs[r * 72 + tid];
        comp_h[n * 64 + tid] = (_Float16)(s * (1.0f / 40.0f));
    }
}

__device__ __forceinline__ void cnn_body(CnnS& S, int cb_,
    const int* __restrict__ proteins, const _Float16* __restrict__ ehp,
    const half8_t* __restrict__ wtab, const float* __restrict__ b_cnn,
    float* __restrict__ prot_part)
{
    _Float16* bufA = (_Float16*)S.bufA8;
    _Float16* bufB = (_Float16*)S.bufB8;
    half8_t* bufA8 = S.bufA8;
    half8_t* bufB8 = S.bufB8;
    const int tid = threadIdx.x, lane = tid & 63, wid = tid >> 6;
    const int tile = cb_ & 15, p = cb_ >> 4;
    const int t0 = tile * 32;
    const int c0 = wid * 16;
    const int m = lane & 15, g = lane >> 4;

    half8_t z = {};
    for (int e = tid; e < 62 * 9; e += 256) {
        int i = e / 9, a = 1 + (e - 9 * i);
        int gr = t0 - 15 + i;
        half8_t v = z;
        if (gr >= 0 && gr < LP)
            v = *(const half8_t*)&ehp[(size_t)proteins[p * LP + gr] * 80 + 8 * a];
        *(half8_t*)&bufA[i * 128 + (((a & 8) | ((a ^ i) & 7)) << 3)] = v;
    }
    for (int e = tid; e < 62 * 4; e += 256) {
        int i = e >> 2, w = e & 3;
        if (w == 0)      bufA8[i * 16 + (8 | ((10 ^ i) & 7))] = z;
        else if (w == 1) bufB8[i * 16 + ((1 ^ i) & 7)] = z;
        else {
            int blk = 7 + w;
            bufB8[i * 16 + ((blk & 8) | ((blk ^ i) & 7))] = z;
        }
    }

    half8_t wf[11];
    auto load_wf = [&](int L) {
        #pragma unroll
        for (int dr = 0; dr < 11; ++dr) wf[dr] = wtab[L * 11 * 64 + dr * 64 + lane];
    };
    auto conv_tile = [&](const _Float16* src, int r0, float bias) -> f32x4 {
        f32x4 acc = {bias, bias, bias, bias};
        const int B0 = (c0 + 8) >> 3;
        #pragma unroll
        for (int dr = 0; dr < 11; ++dr) {
            int R = r0 - 5 + dr + m;
            int b = B0 + g;
            half8_t a = *(const half8_t*)&src[R * 128 + (((b & 8) | ((b ^ R) & 7)) << 3)];
            acc = __builtin_amdgcn_mfma_f32_16x16x32_f16(a, wf[dr], acc, 0, 0, 0);
        }
        return acc;
    };
    auto store_tile = [&](_Float16* dst, int r0, f32x4 acc) {
        int pc = c0 + 13 + m;
        #pragma unroll
        for (int j = 0; j < 4; ++j) {
            int row = r0 + 4 * g + j;
            int og = t0 - 15 + row;
            float v = fmaxf(acc[j], 0.f);
            dst[swz_off(row, pc)] = (_Float16)((og >= 0 && og < LP) ? v : 0.f);
        }
    };

    load_wf(0);
    __syncthreads();
    {
        float b0 = b_cnn[0];
        const int r0s[4] = {5, 21, 37, 41};
        #pragma unroll
        for (int k = 0; k < 4; ++k) store_tile(bufB, r0s[k], conv_tile(bufA, r0s[k], b0));
    }
    __syncthreads();
    load_wf(1);
    {
        float b1 = b_cnn[1];
        const int r0s[3] = {10, 26, 36};
        #pragma unroll
        for (int k = 0; k < 3; ++k) store_tile(bufA, r0s[k], conv_tile(bufB, r0s[k], b1));
    }
    __syncthreads();
    load_wf(2);
    {
        float b2 = b_cnn[2];
        float cs = 0.f;
        const int r0s[2] = {15, 31};
        #pragma unroll
        for (int k = 0; k < 2; ++k) {
            f32x4 acc = conv_tile(bufA, r0s[k], b2);
            #pragma unroll
            for (int j = 0; j < 4; ++j) cs += fmaxf(acc[j], 0.f);
        }
        cs += __shfl_xor(cs, 16, 64);
        cs += __shfl_xor(cs, 32, 64);
        if (lane < 16)
            prot_part[((size_t)p * 16 + tile) * 64 + c0 + lane] = cs;
    }
}

__device__ __forceinline__ void spk_body(int x, int y,
    const _Float16* __restrict__ Ah, const _Float16* __restrict__ Xt,
    float* __restrict__ part, int M, int Kp)
{
    const int tid = threadIdx.x, wid = tid >> 6, lane = tid & 63;
    const int m = lane & 15, g = lane >> 4;
    const int row0 = x * 64 + wid * 16;
    const int chunk = Kp >> 3, k0 = y * chunk;
    const _Float16* Apr = Ah + (size_t)(row0 + m) * Kp + 8 * g;
    f32x4 acc[4] = {};
    for (int kb = k0; kb < k0 + chunk; kb += 32) {
        half8_t af = *(const half8_t*)&Apr[kb];
        #pragma unroll
        for (int t = 0; t < 4; ++t) {
            half8_t bf = *(const half8_t*)&Xt[(size_t)(t * 16 + m) * Kp + kb + 8 * g];
            acc[t] = __builtin_amdgcn_mfma_f32_16x16x32_f16(af, bf, acc[t], 0, 0, 0);
        }
    }
    #pragma unroll
    for (int t = 0; t < 4; ++t)
        #pragma unroll
        for (int j = 0; j < 4; ++j) {
            int row = row0 + 4 * g + j;
            if (row < M) part[((size_t)y * M + row) * 64 + t * 16 + m] = acc[t][j];
        }
}

__device__ __forceinline__ void epi_body(EpiS& S, int x,
    const float* __restrict__ part, int M, const float* __restrict__ W,
    const float* __restrict__ bias, _Float16* __restrict__ H,
    _Float16* __restrict__ XtN, int Kp)
{
    const int rb = x * 64;
    const int tid = threadIdx.x;
    for (int j = tid; j < 4096; j += 256) S.Ws[j >> 6][j & 63] = W[j];
    for (int j = tid; j < 4096; j += 256) {
        int r = j >> 6, c = j & 63;
        float sum = 0.f;
        if (rb + r < M)
            for (int t = 0; t < 8; ++t) sum += part[((size_t)t * M + rb + r) * 64 + c];
        S.Ys[r][c] = sum;
    }
    __syncthreads();
    const int tx = tid & 15, ty = tid >> 4;
    float acc[4][4];
    #pragma unroll
    for (int i = 0; i < 4; ++i)
        #pragma unroll
        for (int j = 0; j < 4; ++j) acc[i][j] = bias[tx * 4 + j];
    for (int d = 0; d < 64; ++d) {
        float a0 = S.Ys[ty * 4 + 0][d], a1 = S.Ys[ty * 4 + 1][d];
        float a2 = S.Ys[ty * 4 + 2][d], a3 = S.Ys[ty * 4 + 3][d];
        float4 w4 = *(const float4*)&S.Ws[d][tx * 4];
        acc[0][0] += a0 * w4.x; acc[0][1] += a0 * w4.y; acc[0][2] += a0 * w4.z; acc[0][3] += a0 * w4.w;
        acc[1][0] += a1 * w4.x; acc[1][1] += a1 * w4.y; acc[1][2] += a1 * w4.z; acc[1][3] += a1 * w4.w;
        acc[2][0] += a2 * w4.x; acc[2][1] += a2 * w4.y; acc[2][2] += a2 * w4.z; acc[2][3] += a2 * w4.w;
        acc[3][0] += a3 * w4.x; acc[3][1] += a3 * w4.y; acc[3][2] += a3 * w4.z; acc[3][3] += a3 * w4.w;
    }
    #pragma unroll
    for (int i = 0; i < 4; ++i) {
        int row = rb + ty * 4 + i;
        if (row < M) {
            #pragma unroll
            for (int j = 0; j < 4; ++j) {
                int col = tx * 4 + j;
                float v = fmaxf(acc[i][j], 0.f);
                if (H)   H[(size_t)row * 64 + col] = (_Float16)v;
                if (XtN) XtN[(size_t)col * Kp + row] = (_Float16)v;
            }
        }
    }
}

template<int NT, bool GATHER>
__device__ __forceinline__ void mlp_body(MlpS& S, int x, int y,
    const _Float16* __restrict__ A, const int* __restrict__ idx,
    const _Float16* __restrict__ Bt, const float* __restrict__ bias,
    _Float16* __restrict__ C, int K, int N)
{
    const int tid = threadIdx.x, wid = tid >> 6, lane = tid & 63;
    const int m = lane & 15, g = lane >> 4;
    const int row0 = x * 64 + wid * 16;
    const int col0 = y * (NT * 16);
    size_t arow = GATHER ? (size_t)idx[row0 + m] : (size_t)(row0 + m);
    const _Float16* Ap = A + arow * (size_t)K + 8 * g;
    f32x4 acc[NT] = {};
    for (int kb = 0; kb < K; kb += 32) {
        half8_t af = *(const half8_t*)&Ap[kb];
        #pragma unroll
        for (int t = 0; t < NT; ++t) {
            half8_t bf = *(const half8_t*)&Bt[(size_t)(col0 + t * 16 + m) * K + kb + 8 * g];
            acc[t] = __builtin_amdgcn_mfma_f32_16x16x32_f16(af, bf, acc[t], 0, 0, 0);
        }
    }
    const int rr = lane >> 2, c4 = (lane & 3) * 4;
    #pragma unroll
    for (int t = 0; t < NT; ++t) {
        #pragma unroll
        for (int j = 0; j < 4; ++j) S.cb[wid][4 * g + j][m] = acc[t][j];
        half4_t h;
        #pragma unroll
        for (int j = 0; j < 4; ++j)
            h[j] = (_Float16)fmaxf(S.cb[wid][rr][c4 + j] + bias[col0 + t * 16 + c4 + j], 0.f);
        *(half4_t*)&C[(size_t)(row0 + rr) * N + col0 + t * 16 + c4] = h;
    }
}

// =============== MEGA: GNN (blocks 0..NC-1) + CNN (rest) ===============
__global__ __launch_bounds__(256) void mega_kernel(
    const int* __restrict__ proteins, const _Float16* __restrict__ ehp,
    const half8_t* __restrict__ wtab, const float* __restrict__ b_cnn,
    float* __restrict__ prot_part,
    const int* __restrict__ compounds, const float* __restrict__ adjacencies,
    const float* __restrict__ embed_fp, const _Float16* __restrict__ wgt,
    const float* __restrict__ b_gnn, _Float16* __restrict__ comp_h)
{
    __shared__ union { CnnS c; GnnS g; } sm;
    const int bx = blockIdx.x;
    if (bx < NC) {
        gnn_body(sm.g, bx, compounds, adjacencies, embed_fp, wgt, b_gnn, comp_h);
        return;
    }
    cnn_body(sm.c, bx - NC, proteins, ehp, wtab, b_cnn, prot_part);
}

// =============== par1: cnn_reduce + spk1 + mlp1 (independent; LDS 4.4KB) ===============
__global__ __launch_bounds__(256) void par1(
    const float* __restrict__ prot_part, _Float16* __restrict__ prot_h,
    const _Float16* __restrict__ Ah_c, const _Float16* __restrict__ Xt_c, float* __restrict__ part_c,
    const _Float16* __restrict__ Ah_p, const _Float16* __restrict__ Xt_p, float* __restrict__ part_p,
    const _Float16* __restrict__ drug_h, const int* __restrict__ idx_c,
    const _Float16* __restrict__ wd1t, const float* __restrict__ bd1, _Float16* __restrict__ fd1h,
    const _Float16* __restrict__ protf_h, const int* __restrict__ idx_p,
    const _Float16* __restrict__ wp1t, const float* __restrict__ bp1, _Float16* __restrict__ fp1h)
{
    __shared__ MlpS sm;
    int bx = blockIdx.x;
    const int tid = threadIdx.x;
    if (bx < 375) {
        int p = bx * 4 + (tid >> 6), c = tid & 63;
        float s = 0.f;
        for (int t = 0; t < 16; ++t) s += prot_part[((size_t)p * 16 + t) * 64 + c];
        prot_h[p * 64 + c] = (_Float16)(s * (1.0f / 512.0f));
        return;
    }
    bx -= 375;
    if (bx < 512) {
        int z = bx >> 8, rem = bx & 255, y = rem >> 5, x = rem & 31;
        if (z == 0)      spk_body(x, y, Ah_c, Xt_c, part_c, NC, KPC);
        else if (x < 24) spk_body(x, y, Ah_p, Xt_p, part_p, NP, KPP);
        return;
    }
    bx -= 512;
    {
        int z = bx >> 8, rem = bx & 255, y = rem >> 6, x = rem & 63;
        if (z == 0) mlp_body<2, true>(sm, x, y, drug_h, idx_c, wd1t, bd1, fd1h, 1024, 128);
        else        mlp_body<2, true>(sm, x, y, protf_h, idx_p, wp1t, bp1, fp1h, 1024, 128);
    }
}

// =============== par2: epi1 + mlp2 ===============
__global__ __launch_bounds__(256) void par2(
    const float* __restrict__ part_c, const float* __restrict__ W_gcn_d, const float* __restrict__ b_gcn_d,
    _Float16* __restrict__ Xt_ca,
    const float* __restrict__ part_p, const float* __restrict__ W_gcn_p, const float* __restrict__ b_gcn_p,
    _Float16* __restrict__ Xt_pa,
    const _Float16* __restrict__ fd1h, const _Float16* __restrict__ wd2t, const float* __restrict__ bd2,
    _Float16* __restrict__ fd2h,
    const _Float16* __restrict__ fp1h, const _Float16* __restrict__ wp2t, const float* __restrict__ bp2,
    _Float16* __restrict__ fp2h)
{
    __shared__ union { EpiS e; MlpS m; } sm;
    int bx = blockIdx.x;
    if (bx < 64) {
        int z = bx >> 5, x = bx & 31;
        if (z == 0)      epi_body(sm.e, x, part_c, NC, W_gcn_d, b_gcn_d, nullptr, Xt_ca, KPC);
        else if (x < 24) epi_body(sm.e, x, part_p, NP, W_gcn_p, b_gcn_p, nullptr, Xt_pa, KPP);
        return;
    }
    bx -= 64;
    {
        int z = bx >> 8, rem = bx & 255, y = rem >> 6, x = rem & 63;
        if (z == 0) mlp_body<1, false>(sm.m, x, y, fd1h, nullptr, wd2t, bd2, fd2h, 128, 64);
        else        mlp_body<1, false>(sm.m, x, y, fp1h, nullptr, wp2t, bp2, fp2h, 128, 64);
    }
}

// =============== par3: spk2 + mlp3 ===============
__global__ __launch_bounds__(256) void par3(
    const _Float16* __restrict__ Ah_c, const _Float16* __restrict__ Xt_ca, float* __restrict__ part_c,
    const _Float16* __restrict__ Ah_p, const _Float16* __restrict__ Xt_pa, float* __restrict__ part_p,
    const _Float16* __restrict__ fd2h, const _Float16* __restrict__ wd3t, const float* __restrict__ bd3,
    _Float16* __restrict__ fd3h,
    const _Float16* __restrict__ fp2h, const _Float16* __restrict__ wp3t, const float* __restrict__ bp3,
    _Float16* __restrict__ fp3h)
{
    __shared__ MlpS sm;
    int bx = blockIdx.x;
    if (bx < 512) {
        int z = bx >> 8, rem = bx & 255, y = rem >> 5, x = rem & 31;
        if (z == 0)      spk_body(x, y, Ah_c, Xt_ca, part_c, NC, KPC);
        else if (x < 24) spk_body(x, y, Ah_p, Xt_pa, part_p, NP, KPP);
        return;
    }
    bx -= 512;
    {
        int z = bx >> 8, rem = bx & 255, y = rem >> 6, x = rem & 63;
        if (z == 0) mlp_body<1, false>(sm, x, y, fd2h, nullptr, wd3t, bd3, fd3h, 64, 64);
        else        mlp_body<1, false>(sm, x, y, fp2h, nullptr, wp3t, bp3, fp3h, 64, 64);
    }
}

// =============== epi2 (dual) ===============
__global__ __launch_bounds__(256) void epi2_kernel(
    const float* __restrict__ part_c, const float* __restrict__ W0, const float* __restrict__ b0,
    _Float16* __restrict__ Xcb_h,
    const float* __restrict__ part_p, const float* __restrict__ W1, const float* __restrict__ b1,
    _Float16* __restrict__ Xpb_h)
{
    __shared__ EpiS sm;
    int bx = blockIdx.x;
    int z = bx >> 5, x = bx & 31;
    if (z == 0)      epi_body(sm, x, part_c, NC, W0, b0, Xcb_h, nullptr, KPC);
    else if (x < 24) epi_body(sm, x, part_p, NP, W1, b1, Xpb_h, nullptr, KPP);
}

// =============== head kernels ===============
__global__ __launch_bounds__(256) void mfma_head1(
    const int* __restrict__ idx_c, const int* __restrict__ idx_p,
    const _Float16* __restrict__ ci, const _Float16* __restrict__ xc, const _Float16* __restrict__ fd,
    const _Float16* __restrict__ pi, const _Float16* __restrict__ xp, const _Float16* __restrict__ fp,
    const _Float16* __restrict__ Bt, const float* __restrict__ bias, _Float16* __restrict__ C)
{
    const int tid = threadIdx.x, wid = tid >> 6, lane = tid & 63;
    const int m = lane & 15, g = lane >> 4;
    const int row0 = blockIdx.x * 64 + wid * 16;
    const int col0 = blockIdx.y * 32;
    int ic = idx_c[row0 + m], ip = idx_p[row0 + m];
    const _Float16* segs[6] = {
        ci + (size_t)ic * 64 + 8 * g,  xc + (size_t)ic * 64 + 8 * g,
        fd + (size_t)(row0 + m) * 64 + 8 * g,
        pi + (size_t)ip * 64 + 8 * g,  xp + (size_t)ip * 64 + 8 * g,
        fp + (size_t)(row0 + m) * 64 + 8 * g };
    f32x4 acc[2] = {};
    #pragma unroll
    for (int kb = 0; kb < 384; kb += 32) {
        half8_t af = *(const half8_t*)&segs[kb / 64][kb & 63];
        #pragma unroll
        for (int t = 0; t < 2; ++t) {
            half8_t bf = *(const half8_t*)&Bt[(size_t)(col0 + t * 16 + m) * 384 + kb + 8 * g];
            acc[t] = __builtin_amdgcn_mfma_f32_16x16x32_f16(af, bf, acc[t], 0, 0, 0);
        }
    }
    __shared__ MlpS sm;
    const int rr = lane >> 2, c4 = (lane & 3) * 4;
    #pragma unroll
    for (int t = 0; t < 2; ++t) {
        #pragma unroll
        for (int j = 0; j < 4; ++j) sm.cb[wid][4 * g + j][m] = acc[t][j];
        half4_t h;
        #pragma unroll
        for (int j = 0; j < 4; ++j)
            h[j] = (_Float16)fmaxf(sm.cb[wid][rr][c4 + j] + bias[col0 + t * 16 + c4 + j], 0.f);
        *(half4_t*)&C[(size_t)(row0 + rr) * 256 + col0 + t * 16 + c4] = h;
    }
}

__global__ __launch_bounds__(256) void mfma_head2(
    const _Float16* __restrict__ A, const _Float16* __restrict__ Bt,
    const float* __restrict__ bias, _Float16* __restrict__ C)
{
    __shared__ MlpS sm;
    mlp_body<2, false>(sm, blockIdx.x, blockIdx.y, A, nullptr, Bt, bias, C, 256, 256);
}

__global__ __launch_bounds__(256) void mfma_head3(
    const _Float16* __restrict__ A, const _Float16* __restrict__ Bt,
    const float* __restrict__ bias, const float* __restrict__ Wi, const float* __restrict__ bi,
    float* __restrict__ out)
{
    const int tid = threadIdx.x, wid = tid >> 6, lane = tid & 63;
    const int m = lane & 15, g = lane >> 4;
    const int row0 = blockIdx.x * 64 + wid * 16;
    const _Float16* Ap = A + (size_t)(row0 + m) * 256 + 8 * g;
    f32x4 acc[16] = {};
    for (int kb = 0; kb < 256; kb += 32) {
        half8_t af = *(const half8_t*)&Ap[kb];
        #pragma unroll
        for (int t = 0; t < 16; ++t) {
            half8_t bf = *(const half8_t*)&Bt[(size_t)(t * 16 + m) * 256 + kb + 8 * g];
            acc[t] = __builtin_amdgcn_mfma_f32_16x16x32_f16(af, bf, acc[t], 0, 0, 0);
        }
    }
    float p0[4] = {}, p1[4] = {};
    #pragma unroll
    for (int t = 0; t < 16; ++t) {
        float w0 = Wi[(t * 16 + m) * 2], w1 = Wi[(t * 16 + m) * 2 + 1];
        float bc = bias[t * 16 + m];
        #pragma unroll
        for (int j = 0; j < 4; ++j) {
            float v = fmaxf(acc[t][j] + bc, 0.f);
            p0[j] += v * w0; p1[j] += v * w1;
        }
    }
    #pragma unroll
    for (int d = 1; d < 16; d <<= 1) {
        #pragma unroll
        for (int j = 0; j < 4; ++j) {
            p0[j] += __shfl_xor(p0[j], d, 64);
            p1[j] += __shfl_xor(p1[j], d, 64);
        }
    }
    if (m == 0) {
        float B0 = bi[0], B1 = bi[1];
        #pragma unroll
        for (int j = 0; j < 4; ++j) {
            int r = row0 + 4 * g + j;
            out[r * 2 + 0] = 1.f / (1.f + expf(-(p0[j] + B0)));
            out[r * 2 + 1] = 1.f / (1.f + expf(-(p1[j] + B1)));
        }
    }
}

// ======================= launch =======================
extern "C" void kernel_launch(void* const* d_in, const int* in_sizes, int n_in,
                              void* d_out, int out_size, void* d_ws, size_t ws_size,
                              hipStream_t stream)
{
    const int*   idx_c        = (const int*)  d_in[0];
    const int*   idx_p        = (const int*)  d_in[1];
    const int*   compounds    = (const int*)  d_in[2];
    const int*   proteins     = (const int*)  d_in[3];
    const float* adjacencies  = (const float*)d_in[4];
    const float* A_c          = (const float*)d_in[5];
    const float* A_p          = (const float*)d_in[6];
    const float* embed_fp     = (const float*)d_in[7];
    const float* embed_word   = (const float*)d_in[8];
    const float* Xs_c         = (const float*)d_in[9];
    const float* Xs_p         = (const float*)d_in[10];
    const float* drug_feat    = (const float*)d_in[11];
    const float* protein_feat = (const float*)d_in[12];
    const float* W_gnn        = (const float*)d_in[13];
    const float* b_gnn        = (const float*)d_in[14];
    const float* K_cnn        = (const float*)d_in[15];
    const float* b_cnn        = (const float*)d_in[16];
    const float* W_gcn_d      = (const float*)d_in[17];
    const float* b_gcn_d      = (const float*)d_in[18];
    const float* W_gcn_p      = (const float*)d_in[19];
    const float* b_gcn_p      = (const float*)d_in[20];
    const float* Wd1 = (const float*)d_in[21]; const float* bd1 = (const float*)d_in[22];
    const float* Wd2 = (const float*)d_in[23]; const float* bd2 = (const float*)d_in[24];
    const float* Wd3 = (const float*)d_in[25]; const float* bd3 = (const float*)d_in[26];
    const float* Wp1 = (const float*)d_in[27]; const float* bp1 = (const float*)d_in[28];
    const float* Wp2 = (const float*)d_in[29]; const float* bp2 = (const float*)d_in[30];
    const float* Wp3 = (const float*)d_in[31]; const float* bp3 = (const float*)d_in[32];
    const float* Wo1 = (const float*)d_in[33]; const float* bo1 = (const float*)d_in[34];
    const float* Wo2 = (const float*)d_in[35]; const float* bo2 = (const float*)d_in[36];
    const float* Wo3 = (const float*)d_in[37]; const float* bo3 = (const float*)d_in[38];
    const float* W_int = (const float*)d_in[39]; const float* b_int = (const float*)d_in[40];

    float* ws = (float*)d_ws;
    float* prot_part = ws; ws += NP * 16 * 64;
    float* wtab_g    = ws; ws += 8448;
    float* ehp_g     = ws; ws += NW * 40;
    float* part_c    = ws; ws += 8 * NC * 64;
    float* part_p    = ws; ws += 8 * NP * 64;
    _Float16* Ah_c  = (_Float16*)ws; ws += KPC * KPC / 2;
    _Float16* Ah_p  = (_Float16*)ws; ws += KPP * KPP / 2;
    _Float16* Xt_c  = (_Float16*)ws; ws += 32 * KPC;
    _Float16* Xt_p  = (_Float16*)ws; ws += 32 * KPP;
    _Float16* Xt_ca = (_Float16*)ws; ws += 32 * KPC;
    _Float16* Xt_pa = (_Float16*)ws; ws += 32 * KPP;
    _Float16* wgt_g = (_Float16*)ws; ws += 6144;
    _Float16* comp_h  = (_Float16*)ws; ws += NC * 32;
    _Float16* prot_h  = (_Float16*)ws; ws += NP * 32;
    _Float16* Xcb_h   = (_Float16*)ws; ws += NC * 32;
    _Float16* Xpb_h   = (_Float16*)ws; ws += NP * 32;
    _Float16* drug_h  = (_Float16*)ws; ws += NC * 512;
    _Float16* protf_h = (_Float16*)ws; ws += NP * 512;
    _Float16* wd1t = (_Float16*)ws; ws += 65536;
    _Float16* wd2t = (_Float16*)ws; ws += 4096;
    _Float16* wd3t = (_Float16*)ws; ws += 2048;
    _Float16* wp1t = (_Float16*)ws; ws += 65536;
    _Float16* wp2t = (_Float16*)ws; ws += 4096;
    _Float16* wp3t = (_Float16*)ws; ws += 2048;
    _Float16* wo1t = (_Float16*)ws; ws += 49152;
    _Float16* wo2t = (_Float16*)ws; ws += 32768;
    _Float16* wo3t = (_Float16*)ws; ws += 32768;
    _Float16* fd1h = (_Float16*)ws; ws += BSZ * 64;
    _Float16* fd2h = (_Float16*)ws; ws += BSZ * 32;
    _Float16* fd3h = (_Float16*)ws; ws += BSZ * 32;
    _Float16* fp1h = (_Float16*)ws; ws += BSZ * 64;
    _Float16* fp2h = (_Float16*)ws; ws += BSZ * 32;
    _Float16* fp3h = (_Float16*)ws; ws += BSZ * 32;
    _Float16* h1h  = (_Float16*)ws; ws += BSZ * 128;
    _Float16* h2h  = (_Float16*)ws; ws += BSZ * 128;
    (void)ws_size; (void)in_sizes; (void)n_in; (void)out_size;

    prep_all<<<(PREP_TOTAL + 255) / 256, 256, 0, stream>>>(
        K_cnn, (_Float16*)wtab_g, embed_word, (_Float16*)ehp_g,
        drug_feat, protein_feat, Wd1, Wd2, Wd3, Wp1, Wp2, Wp3, Wo1, Wo2, Wo3,
        drug_h, protf_h, wd1t, wd2t, wd3t, wp1t, wp2t, wp3t, wo1t, wo2t, wo3t,
        W_gnn, wgt_g,
        A_c, A_p, Xs_c, Xs_p, Ah_c, Ah_p, Xt_c, Xt_p, Xt_ca, Xt_pa);
    // GNN + CNN (saturating dispatch, 26000 blocks)
    mega_kernel<<<NC + 16 * NP, 256, 0, stream>>>(
        proteins, (const _Float16*)ehp_g, (const half8_t*)wtab_g, b_cnn, prot_part,
        compounds, adjacencies, embed_fp, wgt_g, b_gnn, comp_h);
    // independent follow-ups in one well-occupied launch
    par1<<<375 + 512 + 512, 256, 0, stream>>>(
        prot_part, prot_h,
        Ah_c, Xt_c, part_c, Ah_p, Xt_p, part_p,
        drug_h, idx_c, wd1t, bd1, fd1h, protf_h, idx_p, wp1t, bp1, fp1h);
    par2<<<64 + 512, 256, 0, stream>>>(
        part_c, W_gcn_d, b_gcn_d, Xt_ca, part_p, W_gcn_p, b_gcn_p, Xt_pa,
        fd1h, wd2t, bd2, fd2h, fp1h, wp2t, bp2, fp2h);
    par3<<<512 + 512, 256, 0, stream>>>(
        Ah_c, Xt_ca, part_c, Ah_p, Xt_pa, part_p,
        fd2h, wd3t, bd3, fd3h, fp2h, wp3t, bp3, fp3h);
    epi2_kernel<<<64, 256, 0, stream>>>(
        part_c, W_gcn_d + 4096, b_gcn_d + 64, Xcb_h,
        part_p, W_gcn_p + 4096, b_gcn_p + 64, Xpb_h);
    mfma_head1<<<dim3(64, 8), 256, 0, stream>>>(idx_c, idx_p, comp_h, Xcb_h, fd3h,
                                                prot_h, Xpb_h, fp3h, wo1t, bo1, h1h);
    mfma_head2<<<dim3(64, 8), 256, 0, stream>>>(h1h, wo2t, bo2, h2h);
    mfma_head3<<<64, 256, 0, stream>>>(h2h, wo3t, bo3, W_int, b_int, (float*)d_out);
}